// Round 5
// baseline (153.180 us; speedup 1.0000x reference)
//
#include <hip/hip_runtime.h>
#include <hip/hip_fp16.h>

// NCC loss, fully fused, R12: 4-slice macros (barrier-convoy attack).
// Elimination so far: memory-bound (warm==cold, R8), occupancy (R10: 2x
// blocks/CU -> same per-CU macro rate), LDS pipe (R11: -20% LDS traffic +
// drain removal -> 0.3% change), VALU 40%, MFMA 6%. No pipe >50% busy ->
// the per-macro structure (2 barriers w/ full drains, 3/3/2/2 imbalanced
// chains, dependent ring loads) is the floor: ~6700 cyc/macro for ~1800 cyc
// of pipe work. R12: process 4 slices per barrier pair: NMAC 24->12
// (barriers 48->24), 20 chains = 5/wave perfectly balanced, ring shift-by-4,
// loop overhead halved. Ring prefix arithmetic bit-identical to R11.
// LDS 35.9 KB (4 blocks/CU >= grid 3.75). Staging 576 tasks: 2 prefetched
// per thread + 1 direct-load task on wave 0 (keeps VGPR under the 128 cap).
// Vols: [B=2][D=160][H=192][W=160] fp32. Out: scalar -mean(cc).

#define B_    2
#define D_    160
#define H_    192
#define W_    160
#define HW_   (H_*W_)

// LDS layout (float-word offsets)
#define RS    12                   // raw row stride: 24 taps fp16 = 12 dw, packed
#define SLS   (24*RS)              // 288: raw slice stride
#define FS4   (4*SLS)              // 1152: raw field stride (4 slices)
#define ZROW  (5*FS4)              // 5760: 16 dw of zeros (A2 OOB-row reads)
#define ZEND  (ZROW + 16)          // 5776: end of zero-init region
#define HSUM0 ZEND                 // 5776: 20 chains x 160
#define HCS   160                  // per-(slc,f) hsum block: 16 cols x 10
#define HRS   10                   // hsum col stride (16 h fp16 = 8 dw, pad->10)
#define REDU  (HSUM0 + 20*HCS)     // 8976
#define SMEM  (REDU + 8)           // 8984 dw = 35.9 KB -> 4 blocks/CU
#define DC    40                   // z-chunk depth (grid z = 8)
#define ZCH   (D_/DC)              // 4 z-chunks per batch
#define NMAC  ((DC+8)/4)           // 12 macros x 4 slices
#define W3I   (1.0f/729.0f)
#define NTOT  9830400.0f

#if __has_builtin(__builtin_amdgcn_rcpf)
#define RCP(x) __builtin_amdgcn_rcpf(x)
#else
#define RCP(x) (1.0f/(x))
#endif

typedef _Float16 half8 __attribute__((ext_vector_type(8)));
typedef float    f32x4 __attribute__((ext_vector_type(4)));
typedef unsigned u32x2 __attribute__((ext_vector_type(2)));
#define MFMA16(a,b,c) __builtin_amdgcn_mfma_f32_16x16x32_f16((a),(b),(c),0,0,0)

// permlane swaps: a=VDST, b=VSRC, both updated.
#if __has_builtin(__builtin_amdgcn_permlane32_swap)
#define PL32(a,b) do { u32x2 _s = __builtin_amdgcn_permlane32_swap((a),(b),false,false); \
                       (a)=_s[0]; (b)=_s[1]; } while(0)
#else
#define PL32(a,b) asm volatile("s_nop 1\nv_permlane32_swap_b32 %0, %1" : "+v"(a), "+v"(b))
#endif
#if __has_builtin(__builtin_amdgcn_permlane16_swap)
#define PL16(a,b) do { u32x2 _s = __builtin_amdgcn_permlane16_swap((a),(b),false,false); \
                       (a)=_s[0]; (b)=_s[1]; } while(0)
#else
#define PL16(a,b) asm volatile("s_nop 1\nv_permlane16_swap_b32 %0, %1" : "+v"(a), "+v"(b))
#endif

struct __align__(8) HP { __half2 a, b; };   // 4 fp16 = one b64 LDS word-pair

__global__ __launch_bounds__(256, 4) void ncc_fused(const float* __restrict__ gI,
                                                    const float* __restrict__ gJ,
                                                    float* __restrict__ out)
{
  __shared__ __align__(16) float sm[SMEM];
  const int tid  = threadIdx.x;
  const int lane = tid & 63;
  const int Q    = tid >> 6;
  const int n15  = lane & 15;          // MFMA: A-row m / B-col n / D-col
  const int q4   = lane >> 4;          // MFMA: k-group / D-row quad
  const int w0   = blockIdx.x * 16;
  const int h0   = blockIdx.y * 16;
  const int bz   = blockIdx.z;
  const int bb   = bz / ZCH;
  const int d_lo = (bz % ZCH) * DC;

  // zero raw region + zrow (invalid halo stays 0 forever)
  for (int i = tid; i < ZEND; i += 256) sm[i] = 0.f;

  // shared banded selection fragment: SEL[j] = [n15 <= k <= n15+8], k = 8*q4+j
  half8 SEL;
  #pragma unroll
  for (int j = 0; j < 8; ++j) {
    const int k = 8*q4 + j;
    SEL[j] = (k >= n15 && k <= n15 + 8) ? (_Float16)1 : (_Float16)0;
  }

  // ---------- staging: 576 tasks = 4 slc x 24 r x 6 quads ----------
  // tasks tid, tid+256 prefetched; task tid+512 (tid<64) direct-loaded.
  bool val0 = false, val1 = false, val2 = false;
  int  lo0 = 0, lo1 = 0, lo2 = 0, sc0 = 0, sc1 = 0, sc2 = 0;
  const float *pi0 = gI, *pj0 = gJ, *pi1 = gI, *pj1 = gJ, *pi2 = gI, *pj2 = gJ;
  {
    auto prep = [&](int t, bool& val, int& lo, int& sc,
                    const float*& pi, const float*& pj) {
      if (t >= 576) { val = false; return; }
      sc = t / 144;
      const int u = t - sc*144;
      const int r = u / 6, c = u - r*6;
      const int gh = h0 - 4 + r, gw = w0 - 4 + 4*c;
      val = ((unsigned)gh < (unsigned)H_) && (gw >= 0) && (gw + 3 < W_);
      lo  = sc*SLS + r*RS + 2*c;
      const long off = ((long)(bb*D_ + (d_lo - 4 + sc))*H_ + gh)*(long)W_ + gw;
      pi = gI + off; pj = gJ + off;
    };
    prep(tid,       val0, lo0, sc0, pi0, pj0);
    prep(tid + 256, val1, lo1, sc1, pi1, pj1);
    prep((tid < 64) ? tid + 512 : 576, val2, lo2, sc2, pi2, pj2);
  }

  // ---------- chain bases: wave Q = slice Q, fields i = 0..4 ----------
  int rb_[5], hb_[5];
  #pragma unroll
  for (int i = 0; i < 5; ++i) {
    rb_[i] = i*FS4 + Q*SLS;                   // field i, slice Q
    hb_[i] = HSUM0 + (Q*5 + i)*HCS;           // hsum block = slice*5 + field
  }
  const int a1r = n15*RS + 4*q4;
  const int a2r = (n15 < 8) ? ((16 + n15)*RS + 4*q4) : -1;
  const int zr  = ZROW + 4*q4;

  // ---------- ring: thread owns (h = tid>>4, w = tid&15) ----------
  const int rh = tid >> 4, rw = tid & 15;
  const int rbase = HSUM0 + rw*HRS + (rh >> 1);
  const int rsh   = (rh & 1) * 16;

  float ring[5][9], S[5];
  #pragma unroll
  for (int f = 0; f < 5; ++f) {
    S[f] = 0.f;
    #pragma unroll
    for (int k = 0; k < 9; ++k) ring[f][k] = 0.f;
  }
  float acc = 0.f;

  // ---------- global prefetch (slots 0,1; slot 2 direct-loads) ----------
  float4 f0i = {0,0,0,0}, f0j = {0,0,0,0}, f1i = {0,0,0,0}, f1j = {0,0,0,0};
  int sb_cur = 0;                     // slice base of the macro being staged
  auto fetch = [&](int sbase) {
    sb_cur = sbase;
    if (val0 && (unsigned)(sbase + sc0) < (unsigned)D_) {
      f0i = *(const float4*)pi0; f0j = *(const float4*)pj0;
    } else { f0i = make_float4(0,0,0,0); f0j = make_float4(0,0,0,0); }
    pi0 += 4*HW_; pj0 += 4*HW_;
    if (val1 && (unsigned)(sbase + sc1) < (unsigned)D_) {
      f1i = *(const float4*)pi1; f1j = *(const float4*)pj1;
    } else { f1i = make_float4(0,0,0,0); f1j = make_float4(0,0,0,0); }
    pi1 += 4*HW_; pj1 += 4*HW_;
  };

  auto stage_one = [&](int lo, float4 fi, float4 fj) {
    const __half2 i01 = __floats2half2_rn(fi.x, fi.y);
    const __half2 i23 = __floats2half2_rn(fi.z, fi.w);
    const __half2 j01 = __floats2half2_rn(fj.x, fj.y);
    const __half2 j23 = __floats2half2_rn(fj.z, fj.w);
    HP hI; hI.a = i01; hI.b = i23;
    HP hJ; hJ.a = j01; hJ.b = j23;
    HP h2; h2.a = __hmul2(i01, i01); h2.b = __hmul2(i23, i23);
    HP h3; h3.a = __hmul2(j01, j01); h3.b = __hmul2(j23, j23);
    HP h4; h4.a = __hmul2(i01, j01); h4.b = __hmul2(i23, j23);
    *(HP*)&sm[lo]         = hI;
    *(HP*)&sm[lo +   FS4] = hJ;
    *(HP*)&sm[lo + 2*FS4] = h2;
    *(HP*)&sm[lo + 3*FS4] = h3;
    *(HP*)&sm[lo + 4*FS4] = h4;
  };
  auto stage_write = [&]() {
    // slot 2 (wave 0 only): issue loads first, then stage slots 0,1 under them
    float4 f2i = {0,0,0,0}, f2j = {0,0,0,0};
    const bool do2 = val2 && (unsigned)(sb_cur + sc2) < (unsigned)D_;
    if (do2) { f2i = *(const float4*)pi2; f2j = *(const float4*)pj2; }
    pi2 += 4*HW_; pj2 += 4*HW_;
    if (val0) stage_one(lo0, f0i, f0j);
    if (val1) stage_one(lo1, f1i, f1j);
    if (val2) stage_one(lo2, f2i, f2j);
  };

  // ---- one chain: raw field slice -> hsum (3 MFMAs, transpose in-register) ----
  auto chain = [&](int rb, int hb) {
    const half8 A1 = *(const half8*)&sm[rb + a1r];
    const half8 A2 = (a2r >= 0) ? *(const half8*)&sm[rb + a2r]
                                : *(const half8*)&sm[zr];
    const f32x4 z = {0.f, 0.f, 0.f, 0.f};
    const f32x4 d1 = MFMA16(A1, SEL, z);      // wsum rows 0..15
    const f32x4 d2 = MFMA16(A2, SEL, z);      // wsum rows 16..23 (24..31 = 0)
    unsigned t0 = __builtin_bit_cast(unsigned, __floats2half2_rn(d1[0], d1[1]));
    unsigned t1 = __builtin_bit_cast(unsigned, __floats2half2_rn(d1[2], d1[3]));
    unsigned u0 = __builtin_bit_cast(unsigned, __floats2half2_rn(d2[0], d2[1]));
    unsigned u1 = __builtin_bit_cast(unsigned, __floats2half2_rn(d2[2], d2[3]));
    PL32(t0, u0);
    PL32(t1, u1);
    PL16(t0, u0);
    PL16(t1, u1);
    union { unsigned u[4]; half8 h; } Bv;
    Bv.u[0] = t0; Bv.u[1] = t1; Bv.u[2] = u0; Bv.u[3] = u1;
    const f32x4 dh = MFMA16(SEL, Bv.h, z);    // hsum[m = h][n = w]
    HP ph; ph.a = __floats2half2_rn(dh[0], dh[1]); ph.b = __floats2half2_rn(dh[2], dh[3]);
    *(HP*)&sm[hb + n15*HRS + 2*q4] = ph;      // col w = n15, h = 4q4..4q4+3
  };

  auto h2ext = [&](int addr) -> float {
    const unsigned u = *(const unsigned*)&sm[addr];
    return __half2float(__ushort_as_half((unsigned short)(u >> rsh)));
  };
  auto cc_eval = [&](const float* Sx) {
    const float cr = Sx[4] - Sx[0]*Sx[1]*W3I;
    const float vi = Sx[2] - Sx[0]*Sx[0]*W3I;
    const float vj = Sx[3] - Sx[1]*Sx[1]*W3I;
    acc += cr*cr * RCP(vi*vj + 1e-5f);
  };
  auto ring_cc = [&](int m) {
    float n0[5], n1[5], n2[5], n3[5];
    #pragma unroll
    for (int f = 0; f < 5; ++f) {
      n0[f] = h2ext(rbase + (     f)*HCS);    // slice 0
      n1[f] = h2ext(rbase + ( 5 + f)*HCS);    // slice 1
      n2[f] = h2ext(rbase + (10 + f)*HCS);    // slice 2
      n3[f] = h2ext(rbase + (15 + f)*HCS);    // slice 3
    }
    float SA[5], SB[5], SC[5], SD[5];
    #pragma unroll
    for (int f = 0; f < 5; ++f) {
      SA[f] = S[f]  + n0[f] - ring[f][8];
      SB[f] = SA[f] + n1[f] - ring[f][7];
      SC[f] = SB[f] + n2[f] - ring[f][6];
      SD[f] = SC[f] + n3[f] - ring[f][5];
      S[f]  = SD[f];
      ring[f][8] = ring[f][4]; ring[f][7] = ring[f][3]; ring[f][6] = ring[f][2];
      ring[f][5] = ring[f][1]; ring[f][4] = ring[f][0];
      ring[f][3] = n0[f]; ring[f][2] = n1[f]; ring[f][1] = n2[f]; ring[f][0] = n3[f];
    }
    if (m >= 2) { cc_eval(SA); cc_eval(SB); cc_eval(SC); cc_eval(SD); }
  };

  fetch(d_lo - 4);          // macro 0 slices
  __syncthreads();          // zero-init visible
  stage_write();            // raw macro 0
  fetch(d_lo);              // macro 1 slices
  __syncthreads();          // raw 0 ready

  for (int m = 0; m < NMAC; ++m) {
    #pragma unroll
    for (int i = 0; i < 5; ++i) chain(rb_[i], hb_[i]);
    __syncthreads();                       // hsum (all waves) ready
    if (m + 1 < NMAC) { stage_write(); fetch(d_lo + 4 + 4*m); }  // raw m+1; regs m+2
    ring_cc(m);
    __syncthreads();                       // raw m+1 ready; hsum consumed
  }

  // ---- block reduction -> single atomic ----
  float v = acc;
  #pragma unroll
  for (int off = 32; off > 0; off >>= 1)
    v += __shfl_down(v, off, 64);
  if (lane == 0) sm[REDU + Q] = v;
  __syncthreads();
  if (tid == 0) {
    const float t = sm[REDU] + sm[REDU+1] + sm[REDU+2] + sm[REDU+3];
    atomicAdd(out, -t / NTOT);
  }
}

extern "C" void kernel_launch(void* const* d_in, const int* in_sizes, int n_in,
                              void* d_out, int out_size, void* d_ws, size_t ws_size,
                              hipStream_t stream) {
  const float* J = (const float*)d_in[0];  // y_pred
  const float* I = (const float*)d_in[1];  // y_true (cc symmetric in I,J)
  float* outp = (float*)d_out;
  hipMemsetAsync(d_out, 0, sizeof(float), stream);
  dim3 grid(W_/16, H_/16, B_*ZCH);         // 10 x 12 x 8 = 960 blocks
  ncc_fused<<<grid, dim3(256), 0, stream>>>(I, J, outp);
}

// Round 6
// 139.867 us; speedup vs baseline: 1.0952x; 1.0952x over previous
//
#include <hip/hip_runtime.h>
#include <hip/hip_fp16.h>

// NCC loss, fully fused, R13: cross-barrier software pipeline + DC=80.
// Invariant found R8-R12: wall = block-macros/CU x ~750ns regardless of
// barrier count, LDS traffic, conflicts, balance, residency. Two remaining
// levers: (1) every prior version kept a barrier BETWEEN ring_cc(m) and
// chains(m+1), so the ring's LDS latency + 20-op prefix could never overlap
// the next macro's MFMA work. R13 double-buffers raw (2x11.5KB) and hsum
// (2x6.4KB) -> ONE barrier per macro, body {chains(m); stage(m+1); barrier;
// ring_cc(m)} -> ring flows into chains(m+1) barrier-free. (2) DC 40->80:
// slices/output 1.2->1.1 (-8.3% work), 82.5 block-macros/CU. Chain structure
// (R11 permlane transpose), ring arithmetic bit-identical. LDS 35.9 KB.
// Vols: [B=2][D=160][H=192][W=160] fp32. Out: scalar -mean(cc).

#define B_    2
#define D_    160
#define H_    192
#define W_    160
#define HW_   (H_*W_)

// LDS layout (float-word offsets)
#define RS    12                   // raw row stride: 24 taps fp16 = 12 dw, packed
#define SLS   (24*RS)              // 288: raw slice stride
#define FS    (2*SLS)              // 576: raw field stride (2 slices)
#define RAWSZ (5*FS)               // 2880: one raw buffer (5 fields)
#define ZROW  (2*RAWSZ)            // 5760: 16 dw of zeros (A2 OOB-row reads)
#define ZEND  (ZROW + 16)          // 5776: end of zero-init region
#define HSUM0 ZEND                 // 5776: hsum buffer 0 (10 chains x 160)
#define HCS   160                  // per-(slc,f) hsum block: 16 cols x 10
#define HRS   10                   // hsum col stride (16 h fp16 = 8 dw, pad->10)
#define HSZ   (10*HCS)             // 1600: one hsum buffer
#define REDU  (HSUM0 + 2*HSZ)      // 8976
#define SMEM  (REDU + 8)           // 8984 dw = 35.9 KB -> 4 blocks/CU
#define DC    80                   // z-chunk depth (grid z = 4)
#define ZCH   (D_/DC)              // 2 z-chunks per batch
#define NMAC  ((DC+8)/2)           // 44 macros x 2 slices
#define W3I   (1.0f/729.0f)
#define NTOT  9830400.0f

#if __has_builtin(__builtin_amdgcn_rcpf)
#define RCP(x) __builtin_amdgcn_rcpf(x)
#else
#define RCP(x) (1.0f/(x))
#endif

typedef _Float16 half8 __attribute__((ext_vector_type(8)));
typedef float    f32x4 __attribute__((ext_vector_type(4)));
typedef unsigned u32x2 __attribute__((ext_vector_type(2)));
#define MFMA16(a,b,c) __builtin_amdgcn_mfma_f32_16x16x32_f16((a),(b),(c),0,0,0)

// permlane swaps: a=VDST, b=VSRC, both updated.
#if __has_builtin(__builtin_amdgcn_permlane32_swap)
#define PL32(a,b) do { u32x2 _s = __builtin_amdgcn_permlane32_swap((a),(b),false,false); \
                       (a)=_s[0]; (b)=_s[1]; } while(0)
#else
#define PL32(a,b) asm volatile("s_nop 1\nv_permlane32_swap_b32 %0, %1" : "+v"(a), "+v"(b))
#endif
#if __has_builtin(__builtin_amdgcn_permlane16_swap)
#define PL16(a,b) do { u32x2 _s = __builtin_amdgcn_permlane16_swap((a),(b),false,false); \
                       (a)=_s[0]; (b)=_s[1]; } while(0)
#else
#define PL16(a,b) asm volatile("s_nop 1\nv_permlane16_swap_b32 %0, %1" : "+v"(a), "+v"(b))
#endif

struct __align__(8) HP { __half2 a, b; };   // 4 fp16 = one b64 LDS word-pair

__global__ __launch_bounds__(256, 4) void ncc_fused(const float* __restrict__ gI,
                                                    const float* __restrict__ gJ,
                                                    float* __restrict__ out)
{
  __shared__ __align__(16) float sm[SMEM];
  const int tid  = threadIdx.x;
  const int lane = tid & 63;
  const int Q    = tid >> 6;
  const int n15  = lane & 15;          // MFMA: A-row m / B-col n / D-col
  const int q4   = lane >> 4;          // MFMA: k-group / D-row quad
  const int w0   = blockIdx.x * 16;
  const int h0   = blockIdx.y * 16;
  const int bz   = blockIdx.z;
  const int bb   = bz / ZCH;
  const int d_lo = (bz % ZCH) * DC;

  // zero both raw buffers + zrow (invalid halo stays 0 forever)
  for (int i = tid; i < ZEND; i += 256) sm[i] = 0.f;

  // shared banded selection fragment: SEL[j] = [n15 <= k <= n15+8], k = 8*q4+j
  half8 SEL;
  #pragma unroll
  for (int j = 0; j < 8; ++j) {
    const int k = 8*q4 + j;
    SEL[j] = (k >= n15 && k <= n15 + 8) ? (_Float16)1 : (_Float16)0;
  }

  // ---------- staging: 288 tasks = 2 slc x 24 r x 6 quads ----------
  bool val0 = false, val1 = false;
  int  lo0 = 0, lo1 = 0, sc0 = 0, sc1 = 0;
  const float *pi0 = gI, *pj0 = gJ, *pi1 = gI, *pj1 = gJ;
  {
    auto prep = [&](int t, bool& val, int& lo, int& sc,
                    const float*& pi, const float*& pj) {
      if (t >= 288) { val = false; return; }
      sc = t / 144;
      const int u = t - sc*144;
      const int r = u / 6, c = u - r*6;
      const int gh = h0 - 4 + r, gw = w0 - 4 + 4*c;
      val = ((unsigned)gh < (unsigned)H_) && (gw >= 0) && (gw + 3 < W_);
      lo  = sc*SLS + r*RS + 2*c;
      const long off = ((long)(bb*D_ + (d_lo - 4 + sc))*H_ + gh)*(long)W_ + gw;
      pi = gI + off; pj = gJ + off;
    };
    prep(tid, val0, lo0, sc0, pi0, pj0);
    prep((tid >= 224) ? tid + 32 : 512, val1, lo1, sc1, pi1, pj1);
  }

  // ---------- chain bases: wave Q handles c = Q, Q+4, Q+8 (<10) ----------
  int rb_[3], hb_[3];
  #pragma unroll
  for (int i = 0; i < 3; ++i) {
    int c = Q + 4*i; if (c > 9) c = 9;          // clamped entry unused
    rb_[i] = (c % 5)*FS + (c / 5)*SLS;
    hb_[i] = HSUM0 + c*HCS;
  }
  const int a1r = n15*RS + 4*q4;
  const int a2r = (n15 < 8) ? ((16 + n15)*RS + 4*q4) : -1;
  const int zr  = ZROW + 4*q4;

  // ---------- ring: thread owns (h = tid>>4, w = tid&15) ----------
  const int rh = tid >> 4, rw = tid & 15;
  const int rbase = HSUM0 + rw*HRS + (rh >> 1);
  const int rsh   = (rh & 1) * 16;

  float ring[5][9], S[5];
  #pragma unroll
  for (int f = 0; f < 5; ++f) {
    S[f] = 0.f;
    #pragma unroll
    for (int k = 0; k < 9; ++k) ring[f][k] = 0.f;
  }
  float acc = 0.f;

  // ---------- global prefetch ----------
  float4 f0i = {0,0,0,0}, f0j = {0,0,0,0}, f1i = {0,0,0,0}, f1j = {0,0,0,0};
  auto fetch = [&](int sbase) {
    if (val0 && (unsigned)(sbase + sc0) < (unsigned)D_) {
      f0i = *(const float4*)pi0; f0j = *(const float4*)pj0;
    } else { f0i = make_float4(0,0,0,0); f0j = make_float4(0,0,0,0); }
    pi0 += 2*HW_; pj0 += 2*HW_;
    if (val1 && (unsigned)(sbase + sc1) < (unsigned)D_) {
      f1i = *(const float4*)pi1; f1j = *(const float4*)pj1;
    } else { f1i = make_float4(0,0,0,0); f1j = make_float4(0,0,0,0); }
    pi1 += 2*HW_; pj1 += 2*HW_;
  };

  auto stage_one = [&](int lo, float4 fi, float4 fj) {
    const __half2 i01 = __floats2half2_rn(fi.x, fi.y);
    const __half2 i23 = __floats2half2_rn(fi.z, fi.w);
    const __half2 j01 = __floats2half2_rn(fj.x, fj.y);
    const __half2 j23 = __floats2half2_rn(fj.z, fj.w);
    HP hI; hI.a = i01; hI.b = i23;
    HP hJ; hJ.a = j01; hJ.b = j23;
    HP h2; h2.a = __hmul2(i01, i01); h2.b = __hmul2(i23, i23);
    HP h3; h3.a = __hmul2(j01, j01); h3.b = __hmul2(j23, j23);
    HP h4; h4.a = __hmul2(i01, j01); h4.b = __hmul2(i23, j23);
    *(HP*)&sm[lo]        = hI;
    *(HP*)&sm[lo +   FS] = hJ;
    *(HP*)&sm[lo + 2*FS] = h2;
    *(HP*)&sm[lo + 3*FS] = h3;
    *(HP*)&sm[lo + 4*FS] = h4;
  };
  auto stage_write = [&](int buf) {
    const int b = buf * RAWSZ;
    if (val0) stage_one(b + lo0, f0i, f0j);
    if (val1) stage_one(b + lo1, f1i, f1j);
  };

  // ---- one chain: raw field slice -> hsum (3 MFMAs, transpose in-register) ----
  auto chain = [&](int rb, int hb) {
    const half8 A1 = *(const half8*)&sm[rb + a1r];
    const half8 A2 = (a2r >= 0) ? *(const half8*)&sm[rb + a2r]
                                : *(const half8*)&sm[zr];
    const f32x4 z = {0.f, 0.f, 0.f, 0.f};
    const f32x4 d1 = MFMA16(A1, SEL, z);      // wsum rows 0..15
    const f32x4 d2 = MFMA16(A2, SEL, z);      // wsum rows 16..23 (24..31 = 0)
    unsigned t0 = __builtin_bit_cast(unsigned, __floats2half2_rn(d1[0], d1[1]));
    unsigned t1 = __builtin_bit_cast(unsigned, __floats2half2_rn(d1[2], d1[3]));
    unsigned u0 = __builtin_bit_cast(unsigned, __floats2half2_rn(d2[0], d2[1]));
    unsigned u1 = __builtin_bit_cast(unsigned, __floats2half2_rn(d2[2], d2[3]));
    PL32(t0, u0);
    PL32(t1, u1);
    PL16(t0, u0);
    PL16(t1, u1);
    union { unsigned u[4]; half8 h; } Bv;
    Bv.u[0] = t0; Bv.u[1] = t1; Bv.u[2] = u0; Bv.u[3] = u1;
    const f32x4 dh = MFMA16(SEL, Bv.h, z);    // hsum[m = h][n = w]
    HP ph; ph.a = __floats2half2_rn(dh[0], dh[1]); ph.b = __floats2half2_rn(dh[2], dh[3]);
    *(HP*)&sm[hb + n15*HRS + 2*q4] = ph;      // col w = n15, h = 4q4..4q4+3
  };

  auto h2ext = [&](int addr) -> float {
    const unsigned u = *(const unsigned*)&sm[addr];
    return __half2float(__ushort_as_half((unsigned short)(u >> rsh)));
  };
  auto ring_cc = [&](int m, int hB) {
    float nA[5], nB[5];
    #pragma unroll
    for (int f = 0; f < 5; ++f) {
      nA[f] = h2ext(rbase + hB + f*HCS);      // slice A = chain f
      nB[f] = h2ext(rbase + hB + (5 + f)*HCS);// slice B = chain 5+f
    }
    float SA[5], SB[5];
    #pragma unroll
    for (int f = 0; f < 5; ++f) {
      SA[f] = S[f]  + nA[f] - ring[f][8];
      SB[f] = SA[f] + nB[f] - ring[f][7];
      S[f]  = SB[f];
      #pragma unroll
      for (int k = 8; k >= 2; --k) ring[f][k] = ring[f][k-2];
      ring[f][1] = nA[f]; ring[f][0] = nB[f];
    }
    if (m >= 4) {
      {
        const float cr = SA[4] - SA[0]*SA[1]*W3I;
        const float vi = SA[2] - SA[0]*SA[0]*W3I;
        const float vj = SA[3] - SA[1]*SA[1]*W3I;
        acc += cr*cr * RCP(vi*vj + 1e-5f);
      }
      {
        const float cr = SB[4] - SB[0]*SB[1]*W3I;
        const float vi = SB[2] - SB[0]*SB[0]*W3I;
        const float vj = SB[3] - SB[1]*SB[1]*W3I;
        acc += cr*cr * RCP(vi*vj + 1e-5f);
      }
    }
  };

  fetch(d_lo - 4);          // macro 0 slices
  __syncthreads();          // zero-init visible
  stage_write(0);           // raw macro 0 -> buf 0
  fetch(d_lo - 2);          // macro 1 slices
  __syncthreads();          // raw 0 ready

  // One barrier per macro. Inter-macro hazards covered by double buffers:
  // chains(m) read raw[m&1] (staged before previous barrier), write hsum[m&1];
  // ring_cc(m-1) (concurrent, other side of barrier) reads hsum[(m-1)&1];
  // stage(m+1) writes raw[(m+1)&1] whose readers (chains(m-1)) finished
  // before the previous barrier.
  for (int m = 0; m < NMAC; ++m) {
    const int rB = (m & 1) * RAWSZ;
    const int hB = (m & 1) * HSZ;
    chain(rB + rb_[0], hB + hb_[0]);
    chain(rB + rb_[1], hB + hb_[1]);
    if (Q < 2) chain(rB + rb_[2], hB + hb_[2]);
    if (m + 1 < NMAC) { stage_write((m + 1) & 1); fetch(d_lo + 2*m); }
    __syncthreads();                       // hsum[m&1] + raw[(m+1)&1] ready
    ring_cc(m, hB);                        // overlaps chains(m+1), no barrier
  }

  // ---- block reduction -> single atomic ----
  float v = acc;
  #pragma unroll
  for (int off = 32; off > 0; off >>= 1)
    v += __shfl_down(v, off, 64);
  if (lane == 0) sm[REDU + Q] = v;
  __syncthreads();
  if (tid == 0) {
    const float t = sm[REDU] + sm[REDU+1] + sm[REDU+2] + sm[REDU+3];
    atomicAdd(out, -t / NTOT);
  }
}

extern "C" void kernel_launch(void* const* d_in, const int* in_sizes, int n_in,
                              void* d_out, int out_size, void* d_ws, size_t ws_size,
                              hipStream_t stream) {
  const float* J = (const float*)d_in[0];  // y_pred
  const float* I = (const float*)d_in[1];  // y_true (cc symmetric in I,J)
  float* outp = (float*)d_out;
  hipMemsetAsync(d_out, 0, sizeof(float), stream);
  dim3 grid(W_/16, H_/16, B_*ZCH);         // 10 x 12 x 4 = 480 blocks
  ncc_fused<<<grid, dim3(256), 0, stream>>>(I, J, outp);
}